// Round 10
// baseline (85.277 us; speedup 1.0000x reference)
//
#include <hip/hip_runtime.h>

#define B_TOTAL 32768
#define STRIP   128            // rows per wave
#define TILE    16             // rows per MFMA tile

typedef __attribute__((ext_vector_type(8)))  short    bf16x8;
typedef __attribute__((ext_vector_type(4)))  float    f32x4;
typedef __attribute__((ext_vector_type(4)))  unsigned u32x4;

// round-to-nearest-even fp32 -> bf16 (weights, one-time)
__device__ __forceinline__ unsigned rne1(float f) {
    unsigned u = __builtin_bit_cast(unsigned, f);
    return (u + 0x7FFFu + ((u >> 16) & 1u)) >> 16;
}
// HW packed fp32x2 -> bf16x2 (gfx950; no builtin)
__device__ __forceinline__ unsigned cvtpk(float lo, float hi) {
    unsigned r;
    asm("v_cvt_pk_bf16_f32 %0, %1, %2" : "=v"(r) : "v"(lo), "v"(hi));
    return r;
}
__device__ __forceinline__ float fsig(float v) {
    return __fdividef(1.0f, 1.0f + __expf(-v));
}
__device__ __forceinline__ float ftanh(float v) {
    return 1.0f - __fdividef(2.0f, 1.0f + __expf(2.0f * v));
}

// Weights -> COMPOSITE gate-interleaved fragments for mfma 16x16x32 (as R8).
// Frag F = (s*2 + tau)*8 + ks; B-col n16 = hl*4 + g, so D's j-index gives a
// lane all 4 GATES of one hcol.  Lane l: n16 = l&15 -> g = n16&3, hl = n16>>2;
//   element = W_g[hcol = s*8 + tau*4 + hl][k = ks*32 + (l>>4)*8 + e]
__global__ void wconv_kernel(const float* __restrict__ w1, const float* __restrict__ w2,
                             const float* __restrict__ wf, const float* __restrict__ w3,
                             u32x4* __restrict__ out) {
    int T = blockIdx.x * 256 + threadIdx.x;   // 16384 threads
    int F = T >> 6, l = T & 63;
    int s = F >> 4, tau = (F >> 3) & 1, ks = F & 7;
    int n16 = l & 15;
    int g = n16 & 3, hl = n16 >> 2;
    const float* W = (g == 0) ? w1 : (g == 1) ? w2 : (g == 2) ? wf : w3;
    const float* src = W + (s * 8 + tau * 4 + hl) * 256 + ks * 32 + (l >> 4) * 8;
    f32x4 lo = *(const f32x4*)src;
    f32x4 hi = *(const f32x4*)(src + 4);
    u32x4 r;
    r[0] = rne1(lo[0]) | (rne1(lo[1]) << 16);
    r[1] = rne1(lo[2]) | (rne1(lo[3]) << 16);
    r[2] = rne1(hi[0]) | (rne1(hi[1]) << 16);
    r[3] = rne1(hi[2]) | (rne1(hi[3]) << 16);
    out[T] = r;
}

// Barrier-free, LDS-free. Wave = (row-strip of 128) x (8 hcols x 4 gates).
// Block's 4 waves share the strip (L1 dedups A reads); sgroup = bid&3 picks
// which 32 of 128 cols.  Per 16-row tile: two k-halves, each {cvtpk aged raw
// -> issue next half's 8 loads -> 8 MFMA}.  No __syncthreads anywhere.
__global__ __launch_bounds__(256, 3) void lstm_kernel(
    const float* __restrict__ x, const float* __restrict__ h, const float* __restrict__ c,
    const bf16x8* __restrict__ wfrag,
    const float* __restrict__ b1, const float* __restrict__ b2,
    const float* __restrict__ bfv, const float* __restrict__ b3,
    float* __restrict__ out)
{
    const int tid  = threadIdx.x;
    const int wave = tid >> 6;
    const int lane = tid & 63;
    const int rb   = lane & 15;               // batch row within tile
    const int c4   = lane >> 4;               // 0..3
    const int S    = (blockIdx.x & 3) * 4 + wave;    // col-slice 0..15
    const long strip0 = (long)(blockIdx.x >> 2) * STRIP;
    const int col0 = S * 8 + c4;
    const int col1 = col0 + 4;

    f32x4 raw[8];                             // one k-half in flight (32 VGPR)
    auto ISSUE = [&](long r0, int half) {
        const float* src = (half ? h : x) + (r0 + rb) * 128 + c4 * 8;
#pragma unroll
        for (int k2 = 0; k2 < 4; ++k2) {
            raw[k2 * 2]     = *(const f32x4*)(src + k2 * 32);
            raw[k2 * 2 + 1] = *(const f32x4*)(src + k2 * 32 + 4);
        }
    };

    ISSUE(strip0, 0);                         // start HBM before weight loads

    // resident composite weights: 2 n-tiles x 8 ks -> 64 VGPRs
    bf16x8 wfr[2][8];
#pragma unroll
    for (int tau = 0; tau < 2; ++tau)
#pragma unroll
        for (int ks = 0; ks < 8; ++ks)
            wfr[tau][ks] = wfrag[(size_t)((S * 2 + tau) * 8 + ks) * 64 + lane];

    const f32x4 bias0 = (f32x4){ b1[col0], b2[col0], bfv[col0], b3[col0] };
    const f32x4 bias1 = (f32x4){ b1[col1], b2[col1], bfv[col1], b3[col1] };

    float* out_h = out;
    float* out_c = out + (size_t)B_TOTAL * 128;

#pragma unroll 1
    for (int t = 0; t < STRIP / TILE; ++t) {
        const long gr0 = strip0 + t * TILE;
        const float* crow = c + (gr0 + rb) * 128;
        const float cv0 = crow[col0];
        const float cv1 = crow[col1];

        f32x4 acc0 = bias0, acc1 = bias1;
        bf16x8 hb[4];

        // ---- k-half 0 (x features) ----
#pragma unroll
        for (int k2 = 0; k2 < 4; ++k2) {
            union { unsigned u[4]; bf16x8 v; } pk;
            pk.u[0] = cvtpk(raw[2 * k2][0],     raw[2 * k2][1]);
            pk.u[1] = cvtpk(raw[2 * k2][2],     raw[2 * k2][3]);
            pk.u[2] = cvtpk(raw[2 * k2 + 1][0], raw[2 * k2 + 1][1]);
            pk.u[3] = cvtpk(raw[2 * k2 + 1][2], raw[2 * k2 + 1][3]);
            hb[k2] = pk.v;
        }
        ISSUE(gr0, 1);                        // h-half of this tile
#pragma unroll
        for (int k2 = 0; k2 < 4; ++k2) {
            acc0 = __builtin_amdgcn_mfma_f32_16x16x32_bf16(wfr[0][k2], hb[k2], acc0, 0, 0, 0);
            acc1 = __builtin_amdgcn_mfma_f32_16x16x32_bf16(wfr[1][k2], hb[k2], acc1, 0, 0, 0);
        }

        // ---- k-half 1 (h features) ----
#pragma unroll
        for (int k2 = 0; k2 < 4; ++k2) {
            union { unsigned u[4]; bf16x8 v; } pk;
            pk.u[0] = cvtpk(raw[2 * k2][0],     raw[2 * k2][1]);
            pk.u[1] = cvtpk(raw[2 * k2][2],     raw[2 * k2][3]);
            pk.u[2] = cvtpk(raw[2 * k2 + 1][0], raw[2 * k2 + 1][1]);
            pk.u[3] = cvtpk(raw[2 * k2 + 1][2], raw[2 * k2 + 1][3]);
            hb[k2] = pk.v;
        }
        if (t + 1 < STRIP / TILE) ISSUE(gr0 + TILE, 0);   // x-half of next tile
#pragma unroll
        for (int k2 = 0; k2 < 4; ++k2) {
            acc0 = __builtin_amdgcn_mfma_f32_16x16x32_bf16(wfr[0][4 + k2], hb[k2], acc0, 0, 0, 0);
            acc1 = __builtin_amdgcn_mfma_f32_16x16x32_bf16(wfr[1][4 + k2], hb[k2], acc1, 0, 0, 0);
        }

        // ---- epilogue: lane holds all 4 gates of (rb, col0) and (rb, col1) ----
        const long orow = (gr0 + rb) * 128;
        {
            const float G1 = fsig(acc0[0]);
            const float G2 = fsig(acc0[1]);
            const float GF = ftanh(acc0[2]);
            const float G3 = fsig(acc0[3]);
            const float nc = cv0 * G1 + G2 * GF;
            const float nh = ftanh(nc) * G3;
            out_h[orow + col0] = nh;
            out_c[orow + col0] = nc;
        }
        {
            const float G1 = fsig(acc1[0]);
            const float G2 = fsig(acc1[1]);
            const float GF = ftanh(acc1[2]);
            const float G3 = fsig(acc1[3]);
            const float nc = cv1 * G1 + G2 * GF;
            const float nh = ftanh(nc) * G3;
            out_h[orow + col1] = nh;
            out_c[orow + col1] = nc;
        }
    }
}

extern "C" void kernel_launch(void* const* d_in, const int* in_sizes, int n_in,
                              void* d_out, int out_size, void* d_ws, size_t ws_size,
                              hipStream_t stream) {
    (void)in_sizes; (void)n_in; (void)out_size; (void)ws_size;
    const float* x  = (const float*)d_in[0];
    const float* h  = (const float*)d_in[1];
    const float* c  = (const float*)d_in[2];
    const float* W1 = (const float*)d_in[3];
    const float* b1 = (const float*)d_in[4];
    const float* W2 = (const float*)d_in[5];
    const float* b2 = (const float*)d_in[6];
    const float* Wf = (const float*)d_in[7];
    const float* bf = (const float*)d_in[8];
    const float* W3 = (const float*)d_in[9];
    const float* b3 = (const float*)d_in[10];

    wconv_kernel<<<64, 256, 0, stream>>>(W1, W2, Wf, W3, (u32x4*)d_ws);
    lstm_kernel<<<(B_TOTAL / STRIP) * 4, 256, 0, stream>>>(
        x, h, c, (const bf16x8*)d_ws, b1, b2, bf, b3, (float*)d_out);
}

// Round 11
// 73.331 us; speedup vs baseline: 1.1629x; 1.1629x over previous
//
#include <hip/hip_runtime.h>

#define B_TOTAL 32768
#define NROWB   128            // rows per block
#define TILE    32             // rows per tile
#define NT      4              // tiles per block

typedef __attribute__((ext_vector_type(8)))  short    bf16x8;
typedef __attribute__((ext_vector_type(4)))  float    f32x4;
typedef __attribute__((ext_vector_type(4)))  unsigned u32x4;

// round-to-nearest-even fp32 -> bf16 (weights, one-time)
__device__ __forceinline__ unsigned rne1(float f) {
    unsigned u = __builtin_bit_cast(unsigned, f);
    return (u + 0x7FFFu + ((u >> 16) & 1u)) >> 16;
}
// HW packed fp32x2 -> bf16x2 (gfx950; no builtin)
__device__ __forceinline__ unsigned cvtpk(float lo, float hi) {
    unsigned r;
    asm("v_cvt_pk_bf16_f32 %0, %1, %2" : "=v"(r) : "v"(lo), "v"(hi));
    return r;
}
__device__ __forceinline__ float fsig(float v) {
    return __fdividef(1.0f, 1.0f + __expf(-v));
}
__device__ __forceinline__ float ftanh(float v) {
    return 1.0f - __fdividef(2.0f, 1.0f + __expf(2.0f * v));
}
// DCE guards (rule #17): keep values live without cost
__device__ __forceinline__ void sinkf(float v) { asm volatile("" :: "v"(v)); }
__device__ __forceinline__ void sinkb(const bf16x8& w) {
    union { bf16x8 v; unsigned u[4]; } q; q.v = w;
    asm volatile("" :: "v"(q.u[0]), "v"(q.u[1]), "v"(q.u[2]), "v"(q.u[3]));
}

// Weights -> fragment-linear bf16 for mfma 16x16x32 (R5 layout).
// Frag F = cs*32 + g*8 + ks; lane l: W_g[n = cs*16 + (l&15)][k = ks*32 + (l>>4)*8 + e]
__global__ void wconv_kernel(const float* __restrict__ w1, const float* __restrict__ w2,
                             const float* __restrict__ wf, const float* __restrict__ w3,
                             u32x4* __restrict__ out) {
    int T = blockIdx.x * 256 + threadIdx.x;   // 16384 threads
    int F = T >> 6, l = T & 63;
    int cs = F >> 5, g = (F >> 3) & 3, ks = F & 7;
    const float* W = (g == 0) ? w1 : (g == 1) ? w2 : (g == 2) ? wf : w3;
    const float* s = W + (cs * 16 + (l & 15)) * 256 + ks * 32 + (l >> 4) * 8;
    f32x4 lo = *(const f32x4*)s;
    f32x4 hi = *(const f32x4*)(s + 4);
    u32x4 r;
    r[0] = rne1(lo[0]) | (rne1(lo[1]) << 16);
    r[1] = rne1(lo[2]) | (rne1(lo[3]) << 16);
    r[2] = rne1(hi[0]) | (rne1(hi[1]) << 16);
    r[3] = rne1(hi[2]) | (rne1(hi[3]) << 16);
    out[T] = r;
}

// ABLATION of the R5 structure.  V=0: memory-only (stage+barriers+c+stores).
// V=1: compute-only (LDS-read+cvtpk+MFMA+epilogue math, no global I/O).
// V=2: full R5 kernel (runs LAST -> correct output).
template<int V>
__global__ __launch_bounds__(256, 2) void lstm_kernel(
    const float* __restrict__ x, const float* __restrict__ h, const float* __restrict__ c,
    const bf16x8* __restrict__ wfrag,
    const float* __restrict__ b1, const float* __restrict__ b2,
    const float* __restrict__ bfv, const float* __restrict__ b3,
    float* __restrict__ out)
{
    __shared__ __align__(16) char smem[2][TILE * 1024];   // 64 KB

    const int tid  = threadIdx.x;
    const int wave = tid >> 6;
    const int lane = tid & 63;
    const int cg   = blockIdx.x & 1;
    const long row0 = (long)(blockIdx.x >> 1) * NROWB;
    const int cs   = cg * 4 + wave;
    const int rb   = lane & 15;
    const int gcol4 = cs * 16 + (lane >> 4) * 4;

    auto STAGE = [&](int t) {
        char* buf = smem[t & 1];
        const long gr0 = row0 + (long)t * TILE;
#pragma unroll
        for (int i = 0; i < 8; ++i) {
            const int r = wave * 8 + i;
            const unsigned kb = ((unsigned)lane * 16u) ^ (((unsigned)r & 7u) << 4);
            const float* src = (kb < 512u)
                ? (x + (gr0 + r) * 128 + (kb >> 2))
                : (h + (gr0 + r) * 128 + ((kb - 512u) >> 2));
            __builtin_amdgcn_global_load_lds(
                (const __attribute__((address_space(1))) unsigned*)src,
                (__attribute__((address_space(3))) unsigned*)(buf + r * 1024),
                16, 0, 0);
        }
    };

    if constexpr (V != 1) STAGE(0);

    // weights resident in all variants (pins comparable reg pressure)
    bf16x8 wfr[4][8];
#pragma unroll
    for (int g = 0; g < 4; ++g)
#pragma unroll
        for (int ks = 0; ks < 8; ++ks)
            wfr[g][ks] = wfrag[(size_t)(cs * 32 + g * 8 + ks) * 64 + lane];

    f32x4 bias[4];
    bias[0] = *(const f32x4*)(b1 + gcol4);
    bias[1] = *(const f32x4*)(b2 + gcol4);
    bias[2] = *(const f32x4*)(bfv + gcol4);
    bias[3] = *(const f32x4*)(b3 + gcol4);

    float* out_h = out;
    float* out_c = out + (size_t)B_TOTAL * 128;

#pragma unroll 1
    for (int t = 0; t < NT; ++t) {
        __syncthreads();

        const long gr0 = row0 + (long)t * TILE;

        f32x4 cv[2];
        if constexpr (V == 1) {
            cv[0] = bias[0]; cv[1] = bias[1];      // no global c-read
        } else {
#pragma unroll
            for (int mt = 0; mt < 2; ++mt)
                cv[mt] = *(const f32x4*)(c + (gr0 + mt * 16 + rb) * 128 + gcol4);
        }

        if constexpr (V != 1) { if (t + 1 < NT) STAGE(t + 1); }

        f32x4 acc[2][4];
#pragma unroll
        for (int mt = 0; mt < 2; ++mt)
#pragma unroll
            for (int g = 0; g < 4; ++g)
                acc[mt][g] = (f32x4){0.f, 0.f, 0.f, 0.f};

        if constexpr (V != 0) {
            const char* buf = smem[t & 1];
#pragma unroll
            for (int ks = 0; ks < 8; ++ks) {
                bf16x8 af[2];
#pragma unroll
                for (int mt = 0; mt < 2; ++mt) {
                    const int r = mt * 16 + rb;
                    const unsigned swz = ((unsigned)r & 7u) << 4;
                    const unsigned kb  = (unsigned)(ks * 128 + (lane >> 4) * 32);
                    const char* p = buf + r * 1024;
                    f32x4 a0 = *(const f32x4*)(p + (kb ^ swz));
                    f32x4 a1 = *(const f32x4*)(p + ((kb + 16u) ^ swz));
                    union { unsigned u[4]; bf16x8 v; } pk;
                    pk.u[0] = cvtpk(a0[0], a0[1]);
                    pk.u[1] = cvtpk(a0[2], a0[3]);
                    pk.u[2] = cvtpk(a1[0], a1[1]);
                    pk.u[3] = cvtpk(a1[2], a1[3]);
                    af[mt] = pk.v;
                }
#pragma unroll
                for (int g = 0; g < 4; ++g) {
                    acc[0][g] = __builtin_amdgcn_mfma_f32_16x16x32_bf16(wfr[g][ks], af[0], acc[0][g], 0, 0, 0);
                    acc[1][g] = __builtin_amdgcn_mfma_f32_16x16x32_bf16(wfr[g][ks], af[1], acc[1][g], 0, 0, 0);
                }
            }
        }

        // epilogue
#pragma unroll
        for (int mt = 0; mt < 2; ++mt) {
            const long o = (gr0 + mt * 16 + rb) * 128 + gcol4;
            if constexpr (V == 0) {
                // memory-only: preserve the two float4 stores, data = cv
                *(f32x4*)(out_h + o) = cv[mt];
                *(f32x4*)(out_c + o) = cv[mt];
            } else {
                f32x4 nh, nc;
#pragma unroll
                for (int j = 0; j < 4; ++j) {
                    const float g1 = fsig(acc[mt][0][j] + bias[0][j]);
                    const float g2 = fsig(acc[mt][1][j] + bias[1][j]);
                    const float gf = ftanh(acc[mt][2][j] + bias[2][j]);
                    const float g3 = fsig(acc[mt][3][j] + bias[3][j]);
                    nc[j] = cv[mt][j] * g1 + g2 * gf;
                    nh[j] = ftanh(nc[j]) * g3;
                }
                if constexpr (V == 1) {
#pragma unroll
                    for (int j = 0; j < 4; ++j) { sinkf(nh[j]); sinkf(nc[j]); }
                } else {
                    *(f32x4*)(out_h + o) = nh;
                    *(f32x4*)(out_c + o) = nc;
                }
            }
        }

        if constexpr (V == 0) {
            // keep resident weights live across the whole loop (reg-pressure pin)
#pragma unroll
            for (int g = 0; g < 4; ++g)
#pragma unroll
                for (int ks = 0; ks < 8; ++ks) sinkb(wfr[g][ks]);
        }
    }
}

extern "C" void kernel_launch(void* const* d_in, const int* in_sizes, int n_in,
                              void* d_out, int out_size, void* d_ws, size_t ws_size,
                              hipStream_t stream) {
    (void)in_sizes; (void)n_in; (void)out_size; (void)ws_size;
    const float* x  = (const float*)d_in[0];
    const float* h  = (const float*)d_in[1];
    const float* c  = (const float*)d_in[2];
    const float* W1 = (const float*)d_in[3];
    const float* b1 = (const float*)d_in[4];
    const float* W2 = (const float*)d_in[5];
    const float* b2 = (const float*)d_in[6];
    const float* Wf = (const float*)d_in[7];
    const float* bf = (const float*)d_in[8];
    const float* W3 = (const float*)d_in[9];
    const float* b3 = (const float*)d_in[10];

    wconv_kernel<<<64, 256, 0, stream>>>(W1, W2, Wf, W3, (u32x4*)d_ws);
    const int grid = B_TOTAL / NROWB * 2;
    // V0 (memory-only) and V1 (compute-only) are ablation probes; V2 runs
    // last and produces the final correct output (harness re-validates).
    lstm_kernel<0><<<grid, 256, 0, stream>>>(x, h, c, (const bf16x8*)d_ws, b1, b2, bf, b3, (float*)d_out);
    lstm_kernel<1><<<grid, 256, 0, stream>>>(x, h, c, (const bf16x8*)d_ws, b1, b2, bf, b3, (float*)d_out);
    lstm_kernel<2><<<grid, 256, 0, stream>>>(x, h, c, (const bf16x8*)d_ws, b1, b2, bf, b3, (float*)d_out);
}

// Round 12
// 36.637 us; speedup vs baseline: 2.3276x; 2.0016x over previous
//
#include <hip/hip_runtime.h>

#define B_TOTAL 32768
#define NROWB   128            // rows per block
#define TILE    16             // rows per tile
#define NT      8              // tiles per block
#define BUFS    4              // LDS ring buffers

typedef __attribute__((ext_vector_type(8)))  short    bf16x8;
typedef __attribute__((ext_vector_type(4)))  float    f32x4;
typedef __attribute__((ext_vector_type(4)))  unsigned u32x4;

// round-to-nearest-even fp32 -> bf16 (weights, one-time)
__device__ __forceinline__ unsigned rne1(float f) {
    unsigned u = __builtin_bit_cast(unsigned, f);
    return (u + 0x7FFFu + ((u >> 16) & 1u)) >> 16;
}
// HW packed fp32x2 -> bf16x2 (gfx950; no builtin)
__device__ __forceinline__ unsigned cvtpk(float lo, float hi) {
    unsigned r;
    asm("v_cvt_pk_bf16_f32 %0, %1, %2" : "=v"(r) : "v"(lo), "v"(hi));
    return r;
}
__device__ __forceinline__ float fsig(float v) {
    return __fdividef(1.0f, 1.0f + __expf(-v));
}
__device__ __forceinline__ float ftanh(float v) {
    return 1.0f - __fdividef(2.0f, 1.0f + __expf(2.0f * v));
}

// Weights -> fragment-linear bf16 for mfma 16x16x32 (R5 layout).
// Frag F = cs*32 + g*8 + ks; lane l: W_g[n = cs*16 + (l&15)][k = ks*32 + (l>>4)*8 + e]
__global__ void wconv_kernel(const float* __restrict__ w1, const float* __restrict__ w2,
                             const float* __restrict__ wf, const float* __restrict__ w3,
                             u32x4* __restrict__ out) {
    int T = blockIdx.x * 256 + threadIdx.x;   // 16384 threads
    int F = T >> 6, l = T & 63;
    int cs = F >> 5, g = (F >> 3) & 3, ks = F & 7;
    const float* W = (g == 0) ? w1 : (g == 1) ? w2 : (g == 2) ? wf : w3;
    const float* s = W + (cs * 16 + (l & 15)) * 256 + ks * 32 + (l >> 4) * 8;
    f32x4 lo = *(const f32x4*)s;
    f32x4 hi = *(const f32x4*)(s + 4);
    u32x4 r;
    r[0] = rne1(lo[0]) | (rne1(lo[1]) << 16);
    r[1] = rne1(lo[2]) | (rne1(lo[3]) << 16);
    r[2] = rne1(hi[0]) | (rne1(hi[1]) << 16);
    r[3] = rne1(hi[2]) | (rne1(hi[3]) << 16);
    out[T] = r;
}

// Counted-vmcnt pipeline (T3/T4): 4-buffer LDS ring, stage depth 2,
// raw s_barrier + manual s_waitcnt vmcnt(14) -- NEVER vmcnt(0) in the loop.
// Every body issues exactly 7 VMEM ops (4 stage + 2 stores + 1 c-load,
// tail-clamped) so the count is uniform:
//   newer-than-stage(t) at its wait = 3 (t-2: stores+cv) + 7 (t-1) + 4 (t) = 14.
// Buffer reuse safe: body t writes buf (t+2)&3; all waves passed barrier(t-1)
// => finished body(t-2), the last reader of that buffer.
__global__ __launch_bounds__(256, 2) void lstm_kernel(
    const float* __restrict__ x, const float* __restrict__ h, const float* __restrict__ c,
    const bf16x8* __restrict__ wfrag,
    const float* __restrict__ b1, const float* __restrict__ b2,
    const float* __restrict__ bfv, const float* __restrict__ b3,
    float* __restrict__ out)
{
    __shared__ __align__(16) char smem[BUFS][TILE * 1024];   // 64 KB

    const int tid  = threadIdx.x;
    const int wave = tid >> 6;
    const int lane = tid & 63;
    const int cg   = blockIdx.x & 1;
    const long row0 = (long)(blockIdx.x >> 1) * NROWB;
    const int cs   = cg * 4 + wave;
    const int rb   = lane & 15;
    const int c4   = lane >> 4;
    const int gcol4 = cs * 16 + c4 * 4;

    // stage tile t (16 rows x 256 fp32), 4 rows per wave, source-XOR swizzle.
    // t >= NT clamps to tile NT-1 (keeps VMEM op count uniform; data unused).
    auto STAGE = [&](int t) {
        const int tc = (t < NT) ? t : (NT - 1);
        char* buf = smem[t & (BUFS - 1)];
        const long gr0 = row0 + (long)tc * TILE;
#pragma unroll
        for (int i = 0; i < 4; ++i) {
            const int r = wave * 4 + i;
            const unsigned kb = ((unsigned)lane * 16u) ^ (((unsigned)r & 7u) << 4);
            const float* src = (kb < 512u)
                ? (x + (gr0 + r) * 128 + (kb >> 2))
                : (h + (gr0 + r) * 128 + ((kb - 512u) >> 2));
            __builtin_amdgcn_global_load_lds(
                (const __attribute__((address_space(1))) unsigned*)src,
                (__attribute__((address_space(3))) unsigned*)(buf + r * 1024),
                16, 0, 0);
        }
    };

    STAGE(0);
    STAGE(1);

    // resident weights: 4 gates x 8 ks -> 128 VGPRs (loaded once, L2-hot)
    bf16x8 wfr[4][8];
#pragma unroll
    for (int g = 0; g < 4; ++g)
#pragma unroll
        for (int ks = 0; ks < 8; ++ks)
            wfr[g][ks] = wfrag[(size_t)(cs * 32 + g * 8 + ks) * 64 + lane];

    f32x4 bias[4];
    bias[0] = *(const f32x4*)(b1 + gcol4);
    bias[1] = *(const f32x4*)(b2 + gcol4);
    bias[2] = *(const f32x4*)(bfv + gcol4);
    bias[3] = *(const f32x4*)(b3 + gcol4);

    // c prefetch, depth 2 (parity registers; reloaded after use -> static idx)
    f32x4 cvA = *(const f32x4*)(c + (row0 + 0 * TILE + rb) * 128 + gcol4);
    f32x4 cvB = *(const f32x4*)(c + (row0 + 1 * TILE + rb) * 128 + gcol4);

    float* out_h = out;
    float* out_c = out + (size_t)B_TOTAL * 128;

    auto BODY = [&](int t, f32x4& cv) {
        STAGE(t + 2);                          // 4 VMEM, writes buf (t+2)&3
        asm volatile("s_waitcnt vmcnt(14)" ::: "memory");   // stage(t) done
        __builtin_amdgcn_s_barrier();          // raw: no implicit drain
        __builtin_amdgcn_sched_barrier(0);     // pin ds_reads after barrier

        const char* buf = smem[t & (BUFS - 1)];
        const long gr0 = row0 + (long)t * TILE;

        f32x4 acc[4] = { bias[0], bias[1], bias[2], bias[3] };
#pragma unroll
        for (int ks = 0; ks < 8; ++ks) {
            const unsigned swz = ((unsigned)rb & 7u) << 4;
            const unsigned kb  = (unsigned)(ks * 128 + c4 * 32);
            const char* p = buf + rb * 1024;
            f32x4 a0 = *(const f32x4*)(p + (kb ^ swz));
            f32x4 a1 = *(const f32x4*)(p + ((kb + 16u) ^ swz));
            union { unsigned u[4]; bf16x8 v; } pk;
            pk.u[0] = cvtpk(a0[0], a0[1]);
            pk.u[1] = cvtpk(a0[2], a0[3]);
            pk.u[2] = cvtpk(a1[0], a1[1]);
            pk.u[3] = cvtpk(a1[2], a1[3]);
#pragma unroll
            for (int g = 0; g < 4; ++g)        // swapped operands: D[gatecol][row]
                acc[g] = __builtin_amdgcn_mfma_f32_16x16x32_bf16(wfr[g][ks], pk.v, acc[g], 0, 0, 0);
        }

        // epilogue: lane holds 4 gate-cols of one row; float4 stores (2 VMEM)
        f32x4 nh, nc;
#pragma unroll
        for (int j = 0; j < 4; ++j) {
            const float g1 = fsig(acc[0][j]);
            const float g2 = fsig(acc[1][j]);
            const float gf = ftanh(acc[2][j]);
            const float g3 = fsig(acc[3][j]);
            nc[j] = cv[j] * g1 + g2 * gf;
            nh[j] = ftanh(nc[j]) * g3;
        }
        const long o = (gr0 + rb) * 128 + gcol4;
        *(f32x4*)(out_h + o) = nh;
        *(f32x4*)(out_c + o) = nc;

        // reload this parity's c for tile t+2 (1 VMEM; clamped at tail)
        const int tc2 = (t + 2 < NT) ? (t + 2) : (NT - 1);
        cv = *(const f32x4*)(c + (row0 + (long)tc2 * TILE + rb) * 128 + gcol4);
    };

#pragma unroll 1
    for (int tt = 0; tt < NT; tt += 2) {
        BODY(tt,     cvA);
        BODY(tt + 1, cvB);
    }
}

extern "C" void kernel_launch(void* const* d_in, const int* in_sizes, int n_in,
                              void* d_out, int out_size, void* d_ws, size_t ws_size,
                              hipStream_t stream) {
    (void)in_sizes; (void)n_in; (void)out_size; (void)ws_size;
    const float* x  = (const float*)d_in[0];
    const float* h  = (const float*)d_in[1];
    const float* c  = (const float*)d_in[2];
    const float* W1 = (const float*)d_in[3];
    const float* b1 = (const float*)d_in[4];
    const float* W2 = (const float*)d_in[5];
    const float* b2 = (const float*)d_in[6];
    const float* Wf = (const float*)d_in[7];
    const float* bf = (const float*)d_in[8];
    const float* W3 = (const float*)d_in[9];
    const float* b3 = (const float*)d_in[10];

    wconv_kernel<<<64, 256, 0, stream>>>(W1, W2, Wf, W3, (u32x4*)d_ws);
    lstm_kernel<<<B_TOTAL / NROWB * 2, 256, 0, stream>>>(
        x, h, c, (const bf16x8*)d_ws, b1, b2, bf, b3, (float*)d_out);
}